// Round 6
// baseline (782.482 us; speedup 1.0000x reference)
//
#include <hip/hip_runtime.h>

using u16 = unsigned short;

typedef __bf16 bf16x8 __attribute__((ext_vector_type(8)));
typedef u16    u16x8  __attribute__((ext_vector_type(8)));
typedef float  f32x4  __attribute__((ext_vector_type(4)));

__device__ __forceinline__ float b2f(u16 u) {
    union { unsigned int i; float f; } c; c.i = ((unsigned int)u) << 16; return c.f;
}
__device__ __forceinline__ u16 f2b(float f) {
    union { float f; unsigned int i; } c; c.f = f;
    unsigned int i = c.i;
    return (u16)((i + 0x7FFFu + ((i >> 16) & 1u)) >> 16);
}
__device__ __forceinline__ unsigned cvtpk(float lo, float hi) {
    unsigned d;
    asm("v_cvt_pk_bf16_f32 %0, %1, %2" : "=v"(d) : "v"(lo), "v"(hi));
    return d;
}

#define AS1 __attribute__((address_space(1)))
#define AS3 __attribute__((address_space(3)))
__device__ __forceinline__ void glds16(const u16* g, u16* l) {
    __builtin_amdgcn_global_load_lds((const AS1 void*)(const void*)g,
                                     (AS3 void*)(void*)l, 16, 0, 0);
}

// ---------------------------------------------------------------------------
// Batched transpose + convert f32 -> bf16: in[b][R][C] f32 -> out[b][C][R] bf16
// ---------------------------------------------------------------------------
__global__ void btrans_f2b(const float* __restrict__ in, u16* __restrict__ out, int R, int C) {
    __shared__ u16 tile[32][33];
    const int c0 = blockIdx.x * 32, r0 = blockIdx.y * 32;
    const size_t base = (size_t)blockIdx.z * R * C;
    const int tx = threadIdx.x, ty = threadIdx.y;
    #pragma unroll
    for (int i = ty; i < 32; i += 8) {
        int r = r0 + i, c = c0 + tx;
        tile[i][tx] = (r < R && c < C) ? f2b(in[base + (size_t)r * C + c]) : (u16)0;
    }
    __syncthreads();
    #pragma unroll
    for (int i = ty; i < 32; i += 8) {
        int c = c0 + i, r = r0 + tx;
        if (c < C && r < R) out[base + (size_t)c * R + r] = tile[tx][i];
    }
}

// Batched transpose + convert bf16 -> f32: in[b][R][C] bf16 -> out[b][C][R] f32
__global__ void btrans_b2f(const u16* __restrict__ in, float* __restrict__ out, int R, int C) {
    __shared__ u16 tile[32][33];
    const int c0 = blockIdx.x * 32, r0 = blockIdx.y * 32;
    const size_t base = (size_t)blockIdx.z * R * C;
    const int tx = threadIdx.x, ty = threadIdx.y;
    #pragma unroll
    for (int i = ty; i < 32; i += 8) {
        int r = r0 + i, c = c0 + tx;
        tile[i][tx] = (r < R && c < C) ? in[base + (size_t)r * C + c] : (u16)0;
    }
    __syncthreads();
    #pragma unroll
    for (int i = ty; i < 32; i += 8) {
        int c = c0 + i, r = r0 + tx;
        if (c < C && r < R) out[base + (size_t)c * R + r] = b2f(tile[tx][i]);
    }
}

// ---------------------------------------------------------------------------
// gemm_bres: C[M,N] = epilogue(A[M,256] @ BT[N,256]^T + bias), K=256 FIXED.
// R10: B-panel-in-registers, K-resident-A-in-LDS, pipelined across M.
// K=256 GEMMs (qkv/proj/W1) were stuck at ~420 TF across three tile shapes:
// with BK=32 there are only 8 K-steps, each paying a barrier + full vmem
// drain (~600cy) against ~300cy of compute. Here the WHOLE K-extent of a
// 64-row A-half is LDS-resident (2 x 32KB dbuf) and each wave holds its
// 32-col B-panel entirely in registers (16 x bf16x8 = 64 VGPR, weights are
// L2-hot and tiny). Inner loop: 8 kt x {2 ds_read_b128 + 4 MFMA}, NO barriers,
// NO global waits. One raw s_barrier + counted vmcnt per half-tile; the next
// half's 4 global_load_lds hide under a full half of compute.
// FIFO-vmcnt drain: first iter vmcnt(0); then vmcnt(8) (EPI0/2: 8 stores
// issued after the stage) / vmcnt(16) (EPI1: +8 residual loads) -> the stage
// loads (oldest) are retired while stores stay in flight.
// A-LDS layout [64][256], 16B slot s of row r holds global chunk s^(r&7)
// (pre-swizzled global source, linear glds dest) -> conflict-free reads.
// Grid: x = N/128 (n-tile), y = G; block handles halves hi = by, by+G, ...
// Waves: 8 as 2M x 4N, wave tile 32x32, acc[2][2].
// EPI: 0 = bias only; 1 = bias+residual+RepBN; 2 = bias+SpatialSiLU
// ---------------------------------------------------------------------------
template<int EPI>
__launch_bounds__(512, 4)
__global__ void gemm_bres(const u16* __restrict__ A, const u16* __restrict__ BT,
                          const float* __restrict__ bias, u16* __restrict__ C,
                          int N, int H, int row0,
                          const u16* __restrict__ R0,
                          const float* __restrict__ g, const float* __restrict__ be,
                          const float* __restrict__ rmv, const float* __restrict__ rvv,
                          const float* __restrict__ alpha,
                          const float* __restrict__ saw, const float* __restrict__ sab) {
    __shared__ __align__(16) u16 SL[2][16384];   // 2 x 32 KB A half-tiles [64][256]
    const int tid = threadIdx.x, wave = tid >> 6, lane = tid & 63;
    const int wm = wave >> 2, wn = wave & 3;     // 2M x 4N
    const int quad = lane >> 4, l16 = lane & 15;
    const int G = gridDim.y;

    // XCD-aware bijective swizzle on flattened block id (consecutive ids share A rows)
    const unsigned gx = gridDim.x;
    unsigned lin = blockIdx.y * gx + blockIdx.x;
    const unsigned nwg = gx * (unsigned)G;
    const unsigned q8 = nwg >> 3, r8 = nwg & 7;
    const unsigned xcd = lin & 7, loc = lin >> 3;
    lin = (xcd < r8 ? xcd * (q8 + 1) : r8 * (q8 + 1) + (xcd - r8) * q8) + loc;
    const int n0 = (int)(lin % gx) * 128;
    const int by = (int)(lin / gx);
    if (by >= H) return;

    // ---- B panel -> registers: wave's 32 cols x K=256 (16 x bf16x8) ----
    bf16x8 bfr[2][8];
    #pragma unroll
    for (int j = 0; j < 2; j++) {
        const size_t rb = (size_t)(n0 + wn * 32 + j * 16 + l16) * 256 + quad * 8;
        #pragma unroll
        for (int kt = 0; kt < 8; kt++)
            bfr[j][kt] = *(const bf16x8*)&BT[rb + kt * 32];
    }

    // ---- A staging offsets: 4 glds16/wave/half; one inst covers 2 rows ----
    // lane l -> row rl = wave*8 + t*2 + (l>>5), slot sl = l&31; LDS slot sl of
    // row rl holds global 16B-chunk sl ^ (rl&7)  (source pre-swizzle).
    int gOff[4], dOff[4];
    #pragma unroll
    for (int t = 0; t < 4; t++) {
        const int rl = wave * 8 + t * 2 + (lane >> 5);
        const int sl = (lane & 31) ^ (rl & 7);
        gOff[t] = rl * 256 + sl * 8;
        dOff[t] = (wave * 8 + t * 2) * 256;
    }

    auto stageA = [&](int buf, int hh) {
        const u16* src = A + (size_t)hh * 16384;
        u16* dst = &SL[buf][0];
        #pragma unroll
        for (int t = 0; t < 4; t++)
            glds16(src + gOff[t], dst + dOff[t]);
    };

    // A-frag read constants (read side undoes the swizzle)
    const int rA0 = wm * 32 + l16;           // rows for i=0; i=1 adds 16 (same &7)
    const int aB0 = rA0 * 256, aB1 = aB0 + 16 * 256;
    const int keyA = l16 & 7;

    // epilogue constants
    const int dup = l16 & 1, pr = l16 >> 1;
    const float alphav = (EPI == 1) ? alpha[0] : 0.f;
    float biasv[2], k0p[2][2], k1p[2][2];
    #pragma unroll
    for (int j = 0; j < 2; j++) {
        biasv[j] = bias[n0 + wn * 32 + j * 16 + l16];
        if (EPI == 1) {
            #pragma unroll
            for (int p = 0; p < 2; p++) {
                const int col = n0 + wn * 32 + j * 16 + pr * 2 + p;
                const float sc = g[col] * rsqrtf(rvv[col] + 1e-5f);
                k1p[j][p] = sc + alphav;
                k0p[j][p] = be[col] - rmv[col] * sc;
            }
        }
    }

    stageA(0, by);
    int cur = 0;
    for (int hi = by; hi < H; hi += G) {
        if (hi == by)       { asm volatile("s_waitcnt vmcnt(0)"  ::: "memory"); }
        else if (EPI == 1)  { asm volatile("s_waitcnt vmcnt(16)" ::: "memory"); }
        else                { asm volatile("s_waitcnt vmcnt(8)"  ::: "memory"); }
        __builtin_amdgcn_s_barrier();
        __builtin_amdgcn_sched_barrier(0);
        const int nxt = cur ^ 1;
        if (hi + G < H) stageA(nxt, hi + G);

        const u16* Ab = &SL[cur][0];
        f32x4 acc[2][2] = {};
        #pragma unroll
        for (int kt = 0; kt < 8; kt++) {
            const int sw = (((kt * 4 + quad) ^ keyA)) * 8;
            bf16x8 a0 = *(const bf16x8*)&Ab[aB0 + sw];
            bf16x8 a1 = *(const bf16x8*)&Ab[aB1 + sw];
            acc[0][0] = __builtin_amdgcn_mfma_f32_16x16x32_bf16(a0, bfr[0][kt], acc[0][0], 0, 0, 0);
            acc[0][1] = __builtin_amdgcn_mfma_f32_16x16x32_bf16(a0, bfr[1][kt], acc[0][1], 0, 0, 0);
            acc[1][0] = __builtin_amdgcn_mfma_f32_16x16x32_bf16(a1, bfr[0][kt], acc[1][0], 0, 0, 0);
            acc[1][1] = __builtin_amdgcn_mfma_f32_16x16x32_bf16(a1, bfr[1][kt], acc[1][1], 0, 0, 0);
        }

        // ---- epilogue for this 64-row half ----
        const int m0h = hi * 64;
        u16* Crow = C + (size_t)(m0h + wm * 32 + quad * 4 + 2 * dup) * N
                      + (n0 + wn * 32 + pr * 2);
        const int r0i = 2 * dup, r1i = r0i + 1;

        #pragma unroll
        for (int i = 0; i < 2; i++) {
            float swv4[4], sbv4[4];
            if (EPI == 2) {
                #pragma unroll
                for (int r = 0; r < 4; r++) {
                    const int rg = row0 + m0h + wm * 32 + i * 16 + quad * 4 + r;
                    const int bidx = rg / 196;
                    swv4[r] = saw[bidx]; sbv4[r] = sab[bidx];
                }
            }
            #pragma unroll
            for (int j = 0; j < 2; j++) {
                float vv[4];
                #pragma unroll
                for (int r = 0; r < 4; r++) {
                    float v = acc[i][j][r] + biasv[j];
                    if (EPI == 2) {
                        const float w = fmaf(swv4[r], v, sbv4[r]);
                        v = v / (1.f + __expf(-w * v));
                    }
                    vv[r] = v;
                }
                float ot[4];
                #pragma unroll
                for (int r = 0; r < 4; r++) ot[r] = __shfl_xor(vv[r], 1, 64);
                float lo0 = dup ? ot[r0i] : vv[r0i], hi0 = dup ? vv[r0i] : ot[r0i];
                float lo1 = dup ? ot[r1i] : vv[r1i], hi1 = dup ? vv[r1i] : ot[r1i];
                if (EPI == 1) {
                    const u16* rp = R0 + (size_t)(m0h + wm * 32 + i * 16 + quad * 4 + r0i) * N
                                       + (n0 + wn * 32 + j * 16 + pr * 2);
                    const unsigned rd0 = *(const unsigned*)rp;
                    const unsigned rd1 = *(const unsigned*)(rp + N);
                    lo0 = fmaf(lo0 + b2f((u16)(rd0 & 0xffff)), k1p[j][0], k0p[j][0]);
                    hi0 = fmaf(hi0 + b2f((u16)(rd0 >> 16)),    k1p[j][1], k0p[j][1]);
                    lo1 = fmaf(lo1 + b2f((u16)(rd1 & 0xffff)), k1p[j][0], k0p[j][0]);
                    hi1 = fmaf(hi1 + b2f((u16)(rd1 >> 16)),    k1p[j][1], k0p[j][1]);
                }
                u16* p = Crow + (size_t)i * 16 * N + j * 16;
                *(unsigned*)p       = cvtpk(lo0, hi0);
                *(unsigned*)(p + N) = cvtpk(lo1, hi1);
            }
        }
        cur = nxt;
    }
}

// ---------------------------------------------------------------------------
// gemm_bt: generic K GEMM (used for W2, K=2048). R9 structure: 256x128 tile,
// BK=32, 8 waves (4M x 2N), 2-buffer 1-barrier K-loop, pair-pack epilogue.
// EPI: 0 = bias only; 1 = bias+residual+RepBN; 2 = bias+SpatialSiLU
// ---------------------------------------------------------------------------
template<int EPI>
__launch_bounds__(512, 4)
__global__ void gemm_bt(const u16* __restrict__ A, const u16* __restrict__ BT,
                        const float* __restrict__ bias, u16* __restrict__ C,
                        int M, int N, int K, int row0,
                        const u16* __restrict__ R0,
                        const float* __restrict__ g, const float* __restrict__ be,
                        const float* __restrict__ rmv, const float* __restrict__ rvv,
                        const float* __restrict__ alpha,
                        const float* __restrict__ saw, const float* __restrict__ sab) {
    __shared__ __align__(16) u16 SL[24576];  // 48 KB: A 2x8192, B 2x4096
    const int tid  = threadIdx.x;
    const int wave = tid >> 6, lane = tid & 63;
    const int wm = wave >> 1, wn = wave & 1;
    const int quad = lane >> 4, l16 = lane & 15;

    const unsigned gx = gridDim.x;
    unsigned lin = blockIdx.y * gx + blockIdx.x;
    const unsigned nwg = gx * gridDim.y;
    const unsigned q8 = nwg >> 3, r8 = nwg & 7;
    const unsigned xcd = lin & 7, loc = lin >> 3;
    lin = (xcd < r8 ? xcd * (q8 + 1) : r8 * (q8 + 1) + (xcd - r8) * q8) + loc;
    const int m0 = (int)(lin / gx) * 256, n0 = (int)(lin % gx) * 128;

    const int srow = lane >> 2;
    const int scol = (((lane & 3) ^ ((srow >> 1) & 3)) * 8);
    const size_t aoff0 = (size_t)(m0 + wave * 32 + srow) * K + scol;
    const size_t aoff1 = aoff0 + (size_t)16 * K;
    const size_t boff  = (size_t)(n0 + wave * 16 + srow) * K + scol;

    const int cfrag = (quad ^ ((l16 >> 1) & 3)) * 8;

    f32x4 acc[4][4] = {};
    const int niter = K >> 5;

    auto stage = [&](int buf, size_t kn) {
        glds16(A  + aoff0 + kn, SL + buf * 8192 + wave * 1024);
        glds16(A  + aoff1 + kn, SL + buf * 8192 + wave * 1024 + 512);
        glds16(BT + boff  + kn, SL + 16384 + buf * 4096 + wave * 512);
    };

    auto kstep = [&](int cur, int kt) {
        __syncthreads();
        if (kt + 1 < niter) stage(cur ^ 1, (size_t)(kt + 1) << 5);
        const u16* ab = SL + cur * 8192;
        const u16* bb = SL + 16384 + cur * 4096;
        bf16x8 af[4], bfr[4];
        #pragma unroll
        for (int i = 0; i < 4; i++)
            af[i] = *(const bf16x8*)&ab[(wm * 64 + i * 16 + l16) * 32 + cfrag];
        #pragma unroll
        for (int j = 0; j < 4; j++)
            bfr[j] = *(const bf16x8*)&bb[(wn * 64 + j * 16 + l16) * 32 + cfrag];
        #pragma unroll
        for (int i = 0; i < 4; i++)
            #pragma unroll
            for (int j = 0; j < 4; j++)
                acc[i][j] = __builtin_amdgcn_mfma_f32_16x16x32_bf16(af[i], bfr[j], acc[i][j], 0, 0, 0);
    };

    stage(0, 0);
    int kt = 0;
    for (; kt + 2 <= niter; kt += 2) { kstep(0, kt); kstep(1, kt + 1); }
    if (kt < niter) kstep(kt & 1, kt);

    __syncthreads();

    float alphav = 0.f;
    if (EPI == 1) alphav = alpha[0];

    float biasv[4], k0v[4], k1v[4];
    #pragma unroll
    for (int j = 0; j < 4; j++) {
        const int col = n0 + wn * 64 + j * 16 + l16;
        biasv[j] = bias[col];
        if (EPI == 1) {
            float sc = g[col] * rsqrtf(rvv[col] + 1e-5f);
            k1v[j] = sc + alphav;
            k0v[j] = be[col] - rmv[col] * sc;
        }
    }

    const int dup = l16 & 1;
    const int pr  = l16 >> 1;
    u16* Crow = C + (size_t)(m0 + wm * 64 + quad * 4 + 2 * dup) * N
                  + (n0 + wn * 64 + pr * 2);

    auto emit = [&]() {
        #pragma unroll
        for (int i = 0; i < 4; i++) {
            float swv4[4], sbv4[4];
            if (EPI == 2) {
                #pragma unroll
                for (int r = 0; r < 4; r++) {
                    const int row = row0 + m0 + wm * 64 + i * 16 + quad * 4 + r;
                    const int bidx = row / 196;
                    swv4[r] = saw[bidx]; sbv4[r] = sab[bidx];
                }
            }
            #pragma unroll
            for (int j = 0; j < 4; j++) {
                float vv[4];
                #pragma unroll
                for (int r = 0; r < 4; r++) {
                    float v = acc[i][j][r] + biasv[j];
                    if (EPI == 1) {
                        const int rowL = (wm & 1) * 64 + i * 16 + quad * 4 + r;
                        const int colp = wn * 64 + j * 16 + (l16 & ~1);
                        unsigned rd = *(const unsigned*)&SL[rowL * 128 + colp];
                        unsigned fb = dup ? (rd & 0xffff0000u) : (rd << 16);
                        union { unsigned u; float f; } cc; cc.u = fb;
                        float x = v + cc.f;
                        v = fmaf(x, k1v[j], k0v[j]);
                    } else if (EPI == 2) {
                        float w = fmaf(swv4[r], v, sbv4[r]);
                        v = v / (1.f + __expf(-w * v));
                    }
                    vv[r] = v;
                }
                unsigned D[4];
                #pragma unroll
                for (int r = 0; r < 4; r++) {
                    float o  = __shfl_xor(vv[r], 1, 64);
                    float lo = dup ? o : vv[r];
                    float hi = dup ? vv[r] : o;
                    D[r] = cvtpk(lo, hi);
                }
                unsigned s0 = dup ? D[2] : D[0];
                unsigned s1 = dup ? D[3] : D[1];
                u16* p = Crow + (size_t)i * 16 * N + j * 16;
                *(unsigned*)p       = s0;
                *(unsigned*)(p + N) = s1;
            }
        }
    };

    if (EPI == 1) {
        #pragma unroll
        for (int h = 0; h < 2; h++) {
            for (int c = tid; c < 2048; c += 512) {
                int row = c >> 4, colc = (c & 15) * 8;
                *(u16x8*)&SL[row * 128 + colc] =
                    *(const u16x8*)&R0[(size_t)(m0 + h * 128 + row) * N + n0 + colc];
            }
            __syncthreads();
            if ((wm >> 1) == h) emit();
            __syncthreads();
        }
    } else {
        emit();
    }
}

// ---------------------------------------------------------------------------
// MFMA flash attention: one block per (local b, h), 4 waves. (unchanged)
// ---------------------------------------------------------------------------
__launch_bounds__(256)
__global__ void attn_kernel(const u16* __restrict__ qkv, u16* __restrict__ o) {
    __shared__ __align__(16) u16 Kb[224 * 32];
    __shared__ __align__(16) u16 Vt[32 * 232];
    __shared__ __align__(16) u16 Pl[4][16 * 232];
    const int tid  = threadIdx.x;
    const int wave = tid >> 6, lane = tid & 63;
    const int quad = lane >> 4, l16 = lane & 15;
    const int b = blockIdx.x >> 3, h = blockIdx.x & 7;
    const u16* qg = qkv + (size_t)b * 196 * 768 + h * 32;
    const float scale = 0.17677669529663687f; // 1/sqrt(32)

    for (int idx = tid; idx < 896; idx += 256) {
        int row = idx >> 2, dp = (idx & 3) * 8;
        u16x8 kv = {};
        if (row < 196) kv = *(const u16x8*)&qg[(size_t)row * 768 + 256 + dp];
        *(u16x8*)&Kb[row * 32 + dp] = kv;
    }
    for (int idx = tid; idx < 224 * 32; idx += 256) {
        int row = idx >> 5, d = idx & 31;
        Vt[d * 232 + row] = (row < 196) ? qg[(size_t)row * 768 + 512 + d] : (u16)0;
    }
    for (int c = lane; c < 16 * 24; c += 64) {
        int m = c / 24, cc = 208 + (c % 24);
        Pl[wave][m * 232 + cc] = 0;
    }
    __syncthreads();

    for (int t = wave; t < 13; t += 4) {
        const int m0 = t * 16;
        bf16x8 aq = {};
        const int qrow = m0 + l16;
        if (qrow < 196) aq = *(const bf16x8*)&qg[(size_t)qrow * 768 + quad * 8];

        f32x4 s[13];
        #pragma unroll
        for (int ct = 0; ct < 13; ct++) {
            bf16x8 bk = *(const bf16x8*)&Kb[(ct * 16 + l16) * 32 + quad * 8];
            s[ct] = __builtin_amdgcn_mfma_f32_16x16x32_bf16(aq, bk, (f32x4){0.f, 0.f, 0.f, 0.f}, 0, 0, 0);
        }
        if (l16 >= 4) {
            #pragma unroll
            for (int r = 0; r < 4; r++) s[12][r] = -1e30f;
        }
        float mx[4] = {-1e30f, -1e30f, -1e30f, -1e30f};
        #pragma unroll
        for (int ct = 0; ct < 13; ct++)
            #pragma unroll
            for (int r = 0; r < 4; r++) mx[r] = fmaxf(mx[r], s[ct][r]);
        #pragma unroll
        for (int off = 1; off < 16; off <<= 1)
            #pragma unroll
            for (int r = 0; r < 4; r++) mx[r] = fmaxf(mx[r], __shfl_xor(mx[r], off, 64));
        float sum[4] = {0.f, 0.f, 0.f, 0.f};
        #pragma unroll
        for (int ct = 0; ct < 13; ct++) {
            #pragma unroll
            for (int r = 0; r < 4; r++) {
                float p = __expf((s[ct][r] - mx[r]) * scale);
                sum[r] += p;
                Pl[wave][(quad * 4 + r) * 232 + ct * 16 + l16] = f2b(p);
            }
        }
        #pragma unroll
        for (int off = 1; off < 16; off <<= 1)
            #pragma unroll
            for (int r = 0; r < 4; r++) sum[r] += __shfl_xor(sum[r], off, 64);
        float inv[4];
        #pragma unroll
        for (int r = 0; r < 4; r++) inv[r] = 1.f / sum[r];

        #pragma unroll
        for (int nt = 0; nt < 2; nt++) {
            f32x4 ao = {0.f, 0.f, 0.f, 0.f};
            #pragma unroll
            for (int kc = 0; kc < 7; kc++) {
                bf16x8 ap = *(const bf16x8*)&Pl[wave][l16 * 232 + kc * 32 + quad * 8];
                bf16x8 bv = *(const bf16x8*)&Vt[(nt * 16 + l16) * 232 + kc * 32 + quad * 8];
                ao = __builtin_amdgcn_mfma_f32_16x16x32_bf16(ap, bv, ao, 0, 0, 0);
            }
            #pragma unroll
            for (int r = 0; r < 4; r++) {
                const int gm = m0 + quad * 4 + r;
                if (gm < 196)
                    o[((size_t)b * 196 + gm) * 256 + h * 32 + nt * 16 + l16] = f2b(ao[r] * inv[r]);
            }
        }
    }
}

// ---------------------------------------------------------------------------
extern "C" void kernel_launch(void* const* d_in, const int* in_sizes, int n_in,
                              void* d_out, int out_size, void* d_ws, size_t ws_size,
                              hipStream_t stream) {
    const float* x      = (const float*)d_in[0];
    const float* Wqkv   = (const float*)d_in[1];
    const float* bqkv   = (const float*)d_in[2];
    const float* Wproj  = (const float*)d_in[3];
    const float* bproj  = (const float*)d_in[4];
    const float* W1     = (const float*)d_in[5];
    const float* b1     = (const float*)d_in[6];
    const float* W2     = (const float*)d_in[7];
    const float* b2     = (const float*)d_in[8];
    const float* saw    = (const float*)d_in[9];
    const float* sab    = (const float*)d_in[10];
    const float* alpha1 = (const float*)d_in[11];
    const float* g1     = (const float*)d_in[12];
    const float* be1    = (const float*)d_in[13];
    const float* rm1    = (const float*)d_in[14];
    const float* rv1    = (const float*)d_in[15];
    const float* alpha2 = (const float*)d_in[16];
    const float* g2     = (const float*)d_in[17];
    const float* be2    = (const float*)d_in[18];
    const float* rm2    = (const float*)d_in[19];
    const float* rv2    = (const float*)d_in[20];

    const int B = 256, Cc = 256, Np = 196, CM = 2048;
    const int M = B * Np; // 50176

    auto al = [](size_t s) { return (s + 255) & ~(size_t)255; };
    char* ws = (char*)d_ws;
    const size_t o_t0  = 0;
    const size_t o_t1  = o_t0 + al((size_t)M * Cc * 2);
    const size_t o_wq  = o_t1 + al((size_t)M * Cc * 2);
    const size_t o_wp  = o_wq + al((size_t)768 * Cc * 2);
    const size_t o_w1  = o_wp + al((size_t)Cc * Cc * 2);
    const size_t o_w2  = o_w1 + al((size_t)Cc * CM * 2);
    const size_t o_scr = o_w2 + al((size_t)CM * Cc * 2);
    const size_t S = (ws_size > o_scr) ? ws_size - o_scr : 0;

    u16* t0     = (u16*)(ws + o_t0);
    u16* t1b    = (u16*)(ws + o_t1);
    u16* WqkvT  = (u16*)(ws + o_wq);
    u16* WprojT = (u16*)(ws + o_wp);
    u16* W1T    = (u16*)(ws + o_w1);
    u16* W2T    = (u16*)(ws + o_w2);
    u16* scr    = (u16*)(ws + o_scr);
    u16* t2     = t0;            // alias: t0 dead after proj epilogue
    u16* obuf   = (u16*)d_out;   // bf16 scratch in f32 d_out; fully rewritten by final btrans
    float* out  = (float*)d_out;

    // chunk counts: M-chunks multiples of 256 (gemm_bt W2 uses 256-row tiles).
    int nq = 1; while (nq < 4 && ((size_t)(M / nq) * 768 * 2) > S) nq *= 2;
    const int nf_opts[6] = {1, 2, 4, 14, 28, 56};
    int nf = 56;
    for (int i = 0; i < 6; ++i) {
        if (((size_t)(M / nf_opts[i]) * CM * 2) <= S) { nf = nf_opts[i]; break; }
    }
    const int Mq = M / nq, Bq = B / nq;
    const int Mf = M / nf;

    dim3 tb(32, 8, 1);
    btrans_f2b<<<dim3((Np + 31) / 32, (Cc + 31) / 32, B), tb, 0, stream>>>(x, t0, Cc, Np);
    btrans_f2b<<<dim3(768 / 32, Cc / 32, 1), tb, 0, stream>>>(Wqkv,  WqkvT,  Cc, 768);
    btrans_f2b<<<dim3(Cc  / 32, Cc / 32, 1), tb, 0, stream>>>(Wproj, WprojT, Cc, Cc);
    btrans_f2b<<<dim3(CM  / 32, Cc / 32, 1), tb, 0, stream>>>(W1,    W1T,    Cc, CM);
    btrans_f2b<<<dim3(Cc  / 32, CM / 32, 1), tb, 0, stream>>>(W2,    W2T,    CM, Cc);

    // qkv + attention, chunked over batches (K=256 -> gemm_bres)
    for (int c = 0; c < nq; ++c) {
        const int Hq = Mq / 64;
        const int Gq = (Hq < 98) ? Hq : 98;
        gemm_bres<0><<<dim3(768 / 128, Gq), 512, 0, stream>>>(
            t0 + (size_t)c * Mq * Cc, WqkvT, bqkv, scr, 768, Hq, 0,
            nullptr, nullptr, nullptr, nullptr, nullptr, nullptr, nullptr, nullptr);
        attn_kernel<<<dim3(Bq * 8), 256, 0, stream>>>(scr, obuf + (size_t)c * Mq * Cc);
    }

    // t1 = RepBN1(t0 + obuf @ Wproj + bproj)  (K=256 -> gemm_bres)
    {
        const int Hp = M / 64;
        const int Gp = (Hp < 392) ? Hp : 392;
        gemm_bres<1><<<dim3(Cc / 128, Gp), 512, 0, stream>>>(
            obuf, WprojT, bproj, t1b, Cc, Hp, 0,
            t0, g1, be1, rm1, rv1, alpha1, nullptr, nullptr);
    }

    // FFN: W1 (K=256 -> gemm_bres), W2 (K=2048 -> gemm_bt)
    for (int c = 0; c < nf; ++c) {
        const int Hf = Mf / 64;
        const int Gf = (Hf < 49) ? Hf : 49;
        gemm_bres<2><<<dim3(CM / 128, Gf), 512, 0, stream>>>(
            t1b + (size_t)c * Mf * Cc, W1T, b1, scr, CM, Hf, c * Mf,
            nullptr, nullptr, nullptr, nullptr, nullptr, nullptr, saw, sab);
        gemm_bt<1><<<dim3(Cc / 128, Mf / 256), 512, 0, stream>>>(
            scr, W2T, b2, t2 + (size_t)c * Mf * Cc, Mf, Cc, CM, 0,
            t1b + (size_t)c * Mf * Cc, g2, be2, rm2, rv2, alpha2, nullptr, nullptr);
    }

    // t2 bf16 [B][N][C] -> out f32 [B][C][N]
    btrans_b2f<<<dim3((Cc + 31) / 32, (Np + 31) / 32, B), tb, 0, stream>>>(t2, out, Np, Cc);
}

// Round 7
// 753.729 us; speedup vs baseline: 1.0381x; 1.0381x over previous
//
#include <hip/hip_runtime.h>

using u16 = unsigned short;

typedef __bf16 bf16x8 __attribute__((ext_vector_type(8)));
typedef u16    u16x8  __attribute__((ext_vector_type(8)));
typedef float  f32x4  __attribute__((ext_vector_type(4)));

__device__ __forceinline__ float b2f(u16 u) {
    union { unsigned int i; float f; } c; c.i = ((unsigned int)u) << 16; return c.f;
}
__device__ __forceinline__ u16 f2b(float f) {
    union { float f; unsigned int i; } c; c.f = f;
    unsigned int i = c.i;
    return (u16)((i + 0x7FFFu + ((i >> 16) & 1u)) >> 16);
}
__device__ __forceinline__ unsigned cvtpk(float lo, float hi) {
    unsigned d;
    asm("v_cvt_pk_bf16_f32 %0, %1, %2" : "=v"(d) : "v"(lo), "v"(hi));
    return d;
}

#define AS1 __attribute__((address_space(1)))
#define AS3 __attribute__((address_space(3)))
__device__ __forceinline__ void glds16(const u16* g, u16* l) {
    __builtin_amdgcn_global_load_lds((const AS1 void*)(const void*)g,
                                     (AS3 void*)(void*)l, 16, 0, 0);
}

// ---------------------------------------------------------------------------
// Batched transpose + convert f32 -> bf16: in[b][R][C] f32 -> out[b][C][R] bf16
// ---------------------------------------------------------------------------
__global__ void btrans_f2b(const float* __restrict__ in, u16* __restrict__ out, int R, int C) {
    __shared__ u16 tile[32][33];
    const int c0 = blockIdx.x * 32, r0 = blockIdx.y * 32;
    const size_t base = (size_t)blockIdx.z * R * C;
    const int tx = threadIdx.x, ty = threadIdx.y;
    #pragma unroll
    for (int i = ty; i < 32; i += 8) {
        int r = r0 + i, c = c0 + tx;
        tile[i][tx] = (r < R && c < C) ? f2b(in[base + (size_t)r * C + c]) : (u16)0;
    }
    __syncthreads();
    #pragma unroll
    for (int i = ty; i < 32; i += 8) {
        int c = c0 + i, r = r0 + tx;
        if (c < C && r < R) out[base + (size_t)c * R + r] = tile[tx][i];
    }
}

// Batched transpose + convert bf16 -> f32: in[b][R][C] bf16 -> out[b][C][R] f32
__global__ void btrans_b2f(const u16* __restrict__ in, float* __restrict__ out, int R, int C) {
    __shared__ u16 tile[32][33];
    const int c0 = blockIdx.x * 32, r0 = blockIdx.y * 32;
    const size_t base = (size_t)blockIdx.z * R * C;
    const int tx = threadIdx.x, ty = threadIdx.y;
    #pragma unroll
    for (int i = ty; i < 32; i += 8) {
        int r = r0 + i, c = c0 + tx;
        tile[i][tx] = (r < R && c < C) ? in[base + (size_t)r * C + c] : (u16)0;
    }
    __syncthreads();
    #pragma unroll
    for (int i = ty; i < 32; i += 8) {
        int c = c0 + i, r = r0 + tx;
        if (c < C && r < R) out[base + (size_t)c * R + r] = b2f(tile[tx][i]);
    }
}

// ---------------------------------------------------------------------------
// gemm_bres: C[M,256] GEMM with K=256 FIXED (qkv/proj/W1).
// R11 = R10 with the register-pressure fix. R10's failure: VGPR_Count=64
// proved the 64-VGPR B-panel was NOT kept resident (total demand ~130 > 128
// cap) -> compiler re-loaded B from global inside the M-loop (~14K cy/half).
// Fix: wave grid 1M x 8N. Each wave owns 16 cols; B-panel = 8 x bf16x8 =
// 32 VGPR. Wave computes all 64 rows x its 16 cols: acc[4] (16 VGPR).
// Total ~90 VGPR < 128 -> panel stays resident.
// A half-tile [64][256] LDS-resident (2 x 32KB dbuf), pipelined across M:
// per half: {vmcnt(N) + barrier} once, stage next half (4 glds/wave),
// 8 kt x {4 ds_read_b128 + 4 MFMA} with no barriers/waits, epilogue.
// vmcnt FIFO: steady top outstanding = [4 stage][(8 resid if EPI1)][8 stores]
// -> vmcnt(8) (EPI0/2) / vmcnt(16) (EPI1) retires exactly the stage loads.
// A-LDS: slot s of row r holds global chunk s^(r&7) (pre-swizzled source,
// linear glds dest); read undoes swizzle with key = l16&7.
// EPI: 0 = bias only; 1 = bias+residual+RepBN; 2 = bias+SpatialSiLU
// ---------------------------------------------------------------------------
template<int EPI>
__launch_bounds__(512, 4)
__global__ void gemm_bres(const u16* __restrict__ A, const u16* __restrict__ BT,
                          const float* __restrict__ bias, u16* __restrict__ C,
                          int N, int H, int row0,
                          const u16* __restrict__ R0,
                          const float* __restrict__ g, const float* __restrict__ be,
                          const float* __restrict__ rmv, const float* __restrict__ rvv,
                          const float* __restrict__ alpha,
                          const float* __restrict__ saw, const float* __restrict__ sab) {
    __shared__ __align__(16) u16 SL[2][16384];   // 2 x 32 KB A half-tiles [64][256]
    const int tid = threadIdx.x, wave = tid >> 6, lane = tid & 63;
    const int quad = lane >> 4, l16 = lane & 15;
    const int G = gridDim.y;

    // XCD-aware bijective swizzle on flattened block id
    const unsigned gx = gridDim.x;
    unsigned lin = blockIdx.y * gx + blockIdx.x;
    const unsigned nwg = gx * (unsigned)G;
    const unsigned q8 = nwg >> 3, r8 = nwg & 7;
    const unsigned xcd = lin & 7, loc = lin >> 3;
    lin = (xcd < r8 ? xcd * (q8 + 1) : r8 * (q8 + 1) + (xcd - r8) * q8) + loc;
    const int n0 = (int)(lin % gx) * 128;
    const int by = (int)(lin / gx);
    if (by >= H) return;

    // ---- B panel -> registers: wave's 16 cols x K=256 (8 x bf16x8 = 32 VGPR)
    bf16x8 bfr[8];
    {
        const size_t rb = (size_t)(n0 + wave * 16 + l16) * 256 + quad * 8;
        #pragma unroll
        for (int kt = 0; kt < 8; kt++)
            bfr[kt] = *(const bf16x8*)&BT[rb + kt * 32];
    }

    // ---- A staging: 4 glds16/wave/half (verified-correct R10 pattern) ----
    int gOff[4], dOff[4];
    #pragma unroll
    for (int t = 0; t < 4; t++) {
        const int rl = wave * 8 + t * 2 + (lane >> 5);
        const int sl = (lane & 31) ^ (rl & 7);
        gOff[t] = rl * 256 + sl * 8;
        dOff[t] = (wave * 8 + t * 2) * 256;
    }

    auto stageA = [&](int buf, int hh) {
        const u16* src = A + (size_t)hh * 16384;
        u16* dst = &SL[buf][0];
        #pragma unroll
        for (int t = 0; t < 4; t++)
            glds16(src + gOff[t], dst + dOff[t]);
    };

    const int keyA = l16 & 7;
    const int aB = l16 * 256;    // row base for i=0; i adds 16*256

    // epilogue constants
    const int dup = l16 & 1, pr = l16 >> 1;
    const float alphav = (EPI == 1) ? alpha[0] : 0.f;
    float biasv, k0p[2], k1p[2];
    biasv = bias[n0 + wave * 16 + l16];
    if (EPI == 1) {
        #pragma unroll
        for (int p = 0; p < 2; p++) {
            const int col = n0 + wave * 16 + pr * 2 + p;
            const float sc = g[col] * rsqrtf(rvv[col] + 1e-5f);
            k1p[p] = sc + alphav;
            k0p[p] = be[col] - rmv[col] * sc;
        }
    }

    stageA(0, by);
    int cur = 0;
    for (int hi = by; hi < H; hi += G) {
        if (hi == by)       { asm volatile("s_waitcnt vmcnt(0)"  ::: "memory"); }
        else if (EPI == 1)  { asm volatile("s_waitcnt vmcnt(16)" ::: "memory"); }
        else                { asm volatile("s_waitcnt vmcnt(8)"  ::: "memory"); }
        __builtin_amdgcn_s_barrier();
        __builtin_amdgcn_sched_barrier(0);
        const int nxt = cur ^ 1;
        if (hi + G < H) stageA(nxt, hi + G);

        const u16* Ab = &SL[cur][0];
        f32x4 acc[4] = {};
        #pragma unroll
        for (int kt = 0; kt < 8; kt++) {
            const int sw = ((kt * 4 + quad) ^ keyA) * 8;
            #pragma unroll
            for (int i = 0; i < 4; i++) {
                bf16x8 a = *(const bf16x8*)&Ab[aB + i * 4096 + sw];
                acc[i] = __builtin_amdgcn_mfma_f32_16x16x32_bf16(a, bfr[kt], acc[i], 0, 0, 0);
            }
        }

        // ---- epilogue for this 64-row half: wave's 64 rows x 16 cols ----
        const int m0h = hi * 64;
        u16* Crow = C + (size_t)(m0h + quad * 4 + 2 * dup) * N
                      + (n0 + wave * 16 + pr * 2);
        const int r0i = 2 * dup, r1i = r0i + 1;

        #pragma unroll
        for (int i = 0; i < 4; i++) {
            float vv[4];
            if (EPI == 2) {
                #pragma unroll
                for (int r = 0; r < 4; r++) {
                    const int rg = row0 + m0h + i * 16 + quad * 4 + r;
                    const int bidx = rg / 196;
                    float v = acc[i][r] + biasv;
                    const float w = fmaf(saw[bidx], v, sab[bidx]);
                    vv[r] = v / (1.f + __expf(-w * v));
                }
            } else {
                #pragma unroll
                for (int r = 0; r < 4; r++) vv[r] = acc[i][r] + biasv;
            }
            float ot[4];
            #pragma unroll
            for (int r = 0; r < 4; r++) ot[r] = __shfl_xor(vv[r], 1, 64);
            float lo0 = dup ? ot[r0i] : vv[r0i], hi0 = dup ? vv[r0i] : ot[r0i];
            float lo1 = dup ? ot[r1i] : vv[r1i], hi1 = dup ? vv[r1i] : ot[r1i];
            if (EPI == 1) {
                const u16* rp = R0 + (size_t)(m0h + i * 16 + quad * 4 + r0i) * N
                                   + (n0 + wave * 16 + pr * 2);
                const unsigned rd0 = *(const unsigned*)rp;
                const unsigned rd1 = *(const unsigned*)(rp + N);
                lo0 = fmaf(lo0 + b2f((u16)(rd0 & 0xffff)), k1p[0], k0p[0]);
                hi0 = fmaf(hi0 + b2f((u16)(rd0 >> 16)),    k1p[1], k0p[1]);
                lo1 = fmaf(lo1 + b2f((u16)(rd1 & 0xffff)), k1p[0], k0p[0]);
                hi1 = fmaf(hi1 + b2f((u16)(rd1 >> 16)),    k1p[1], k0p[1]);
            }
            u16* p = Crow + (size_t)i * 16 * N;
            *(unsigned*)p       = cvtpk(lo0, hi0);
            *(unsigned*)(p + N) = cvtpk(lo1, hi1);
        }
        cur = nxt;
    }
}

// ---------------------------------------------------------------------------
// gemm_bt: generic K GEMM (used for W2, K=2048). R9 structure: 256x128 tile,
// BK=32, 8 waves (4M x 2N), 2-buffer 1-barrier K-loop, pair-pack epilogue.
// EPI: 0 = bias only; 1 = bias+residual+RepBN; 2 = bias+SpatialSiLU
// ---------------------------------------------------------------------------
template<int EPI>
__launch_bounds__(512, 4)
__global__ void gemm_bt(const u16* __restrict__ A, const u16* __restrict__ BT,
                        const float* __restrict__ bias, u16* __restrict__ C,
                        int M, int N, int K, int row0,
                        const u16* __restrict__ R0,
                        const float* __restrict__ g, const float* __restrict__ be,
                        const float* __restrict__ rmv, const float* __restrict__ rvv,
                        const float* __restrict__ alpha,
                        const float* __restrict__ saw, const float* __restrict__ sab) {
    __shared__ __align__(16) u16 SL[24576];  // 48 KB: A 2x8192, B 2x4096
    const int tid  = threadIdx.x;
    const int wave = tid >> 6, lane = tid & 63;
    const int wm = wave >> 1, wn = wave & 1;
    const int quad = lane >> 4, l16 = lane & 15;

    const unsigned gx = gridDim.x;
    unsigned lin = blockIdx.y * gx + blockIdx.x;
    const unsigned nwg = gx * gridDim.y;
    const unsigned q8 = nwg >> 3, r8 = nwg & 7;
    const unsigned xcd = lin & 7, loc = lin >> 3;
    lin = (xcd < r8 ? xcd * (q8 + 1) : r8 * (q8 + 1) + (xcd - r8) * q8) + loc;
    const int m0 = (int)(lin / gx) * 256, n0 = (int)(lin % gx) * 128;

    const int srow = lane >> 2;
    const int scol = (((lane & 3) ^ ((srow >> 1) & 3)) * 8);
    const size_t aoff0 = (size_t)(m0 + wave * 32 + srow) * K + scol;
    const size_t aoff1 = aoff0 + (size_t)16 * K;
    const size_t boff  = (size_t)(n0 + wave * 16 + srow) * K + scol;

    const int cfrag = (quad ^ ((l16 >> 1) & 3)) * 8;

    f32x4 acc[4][4] = {};
    const int niter = K >> 5;

    auto stage = [&](int buf, size_t kn) {
        glds16(A  + aoff0 + kn, SL + buf * 8192 + wave * 1024);
        glds16(A  + aoff1 + kn, SL + buf * 8192 + wave * 1024 + 512);
        glds16(BT + boff  + kn, SL + 16384 + buf * 4096 + wave * 512);
    };

    auto kstep = [&](int cur, int kt) {
        __syncthreads();
        if (kt + 1 < niter) stage(cur ^ 1, (size_t)(kt + 1) << 5);
        const u16* ab = SL + cur * 8192;
        const u16* bb = SL + 16384 + cur * 4096;
        bf16x8 af[4], bfr[4];
        #pragma unroll
        for (int i = 0; i < 4; i++)
            af[i] = *(const bf16x8*)&ab[(wm * 64 + i * 16 + l16) * 32 + cfrag];
        #pragma unroll
        for (int j = 0; j < 4; j++)
            bfr[j] = *(const bf16x8*)&bb[(wn * 64 + j * 16 + l16) * 32 + cfrag];
        #pragma unroll
        for (int i = 0; i < 4; i++)
            #pragma unroll
            for (int j = 0; j < 4; j++)
                acc[i][j] = __builtin_amdgcn_mfma_f32_16x16x32_bf16(af[i], bfr[j], acc[i][j], 0, 0, 0);
    };

    stage(0, 0);
    int kt = 0;
    for (; kt + 2 <= niter; kt += 2) { kstep(0, kt); kstep(1, kt + 1); }
    if (kt < niter) kstep(kt & 1, kt);

    __syncthreads();

    float alphav = 0.f;
    if (EPI == 1) alphav = alpha[0];

    float biasv[4], k0v[4], k1v[4];
    #pragma unroll
    for (int j = 0; j < 4; j++) {
        const int col = n0 + wn * 64 + j * 16 + l16;
        biasv[j] = bias[col];
        if (EPI == 1) {
            float sc = g[col] * rsqrtf(rvv[col] + 1e-5f);
            k1v[j] = sc + alphav;
            k0v[j] = be[col] - rmv[col] * sc;
        }
    }

    const int dup = l16 & 1;
    const int pr  = l16 >> 1;
    u16* Crow = C + (size_t)(m0 + wm * 64 + quad * 4 + 2 * dup) * N
                  + (n0 + wn * 64 + pr * 2);

    auto emit = [&]() {
        #pragma unroll
        for (int i = 0; i < 4; i++) {
            float swv4[4], sbv4[4];
            if (EPI == 2) {
                #pragma unroll
                for (int r = 0; r < 4; r++) {
                    const int row = row0 + m0 + wm * 64 + i * 16 + quad * 4 + r;
                    const int bidx = row / 196;
                    swv4[r] = saw[bidx]; sbv4[r] = sab[bidx];
                }
            }
            #pragma unroll
            for (int j = 0; j < 4; j++) {
                float vv[4];
                #pragma unroll
                for (int r = 0; r < 4; r++) {
                    float v = acc[i][j][r] + biasv[j];
                    if (EPI == 1) {
                        const int rowL = (wm & 1) * 64 + i * 16 + quad * 4 + r;
                        const int colp = wn * 64 + j * 16 + (l16 & ~1);
                        unsigned rd = *(const unsigned*)&SL[rowL * 128 + colp];
                        unsigned fb = dup ? (rd & 0xffff0000u) : (rd << 16);
                        union { unsigned u; float f; } cc; cc.u = fb;
                        float x = v + cc.f;
                        v = fmaf(x, k1v[j], k0v[j]);
                    } else if (EPI == 2) {
                        float w = fmaf(swv4[r], v, sbv4[r]);
                        v = v / (1.f + __expf(-w * v));
                    }
                    vv[r] = v;
                }
                unsigned D[4];
                #pragma unroll
                for (int r = 0; r < 4; r++) {
                    float o  = __shfl_xor(vv[r], 1, 64);
                    float lo = dup ? o : vv[r];
                    float hi = dup ? vv[r] : o;
                    D[r] = cvtpk(lo, hi);
                }
                unsigned s0 = dup ? D[2] : D[0];
                unsigned s1 = dup ? D[3] : D[1];
                u16* p = Crow + (size_t)i * 16 * N + j * 16;
                *(unsigned*)p       = s0;
                *(unsigned*)(p + N) = s1;
            }
        }
    };

    if (EPI == 1) {
        #pragma unroll
        for (int h = 0; h < 2; h++) {
            for (int c = tid; c < 2048; c += 512) {
                int row = c >> 4, colc = (c & 15) * 8;
                *(u16x8*)&SL[row * 128 + colc] =
                    *(const u16x8*)&R0[(size_t)(m0 + h * 128 + row) * N + n0 + colc];
            }
            __syncthreads();
            if ((wm >> 1) == h) emit();
            __syncthreads();
        }
    } else {
        emit();
    }
}

// ---------------------------------------------------------------------------
// MFMA flash attention: one block per (local b, h), 4 waves.
// R11: V staging vectorized (u16x8 row reads instead of stride-1536 scalar).
// ---------------------------------------------------------------------------
__launch_bounds__(256)
__global__ void attn_kernel(const u16* __restrict__ qkv, u16* __restrict__ o) {
    __shared__ __align__(16) u16 Kb[224 * 32];
    __shared__ __align__(16) u16 Vt[32 * 232];
    __shared__ __align__(16) u16 Pl[4][16 * 232];
    const int tid  = threadIdx.x;
    const int wave = tid >> 6, lane = tid & 63;
    const int quad = lane >> 4, l16 = lane & 15;
    const int b = blockIdx.x >> 3, h = blockIdx.x & 7;
    const u16* qg = qkv + (size_t)b * 196 * 768 + h * 32;
    const float scale = 0.17677669529663687f; // 1/sqrt(32)

    for (int idx = tid; idx < 896; idx += 256) {
        int row = idx >> 2, dp = (idx & 3) * 8;
        u16x8 kv = {};
        if (row < 196) kv = *(const u16x8*)&qg[(size_t)row * 768 + 256 + dp];
        *(u16x8*)&Kb[row * 32 + dp] = kv;
    }
    for (int idx = tid; idx < 896; idx += 256) {     // V: vector read, transposed scalar LDS writes
        int row = idx >> 2, dp = (idx & 3) * 8;
        u16x8 vv = {};
        if (row < 196) vv = *(const u16x8*)&qg[(size_t)row * 768 + 512 + dp];
        #pragma unroll
        for (int e = 0; e < 8; e++) Vt[(dp + e) * 232 + row] = vv[e];
    }
    for (int c = lane; c < 16 * 24; c += 64) {
        int m = c / 24, cc = 208 + (c % 24);
        Pl[wave][m * 232 + cc] = 0;
    }
    __syncthreads();

    for (int t = wave; t < 13; t += 4) {
        const int m0 = t * 16;
        bf16x8 aq = {};
        const int qrow = m0 + l16;
        if (qrow < 196) aq = *(const bf16x8*)&qg[(size_t)qrow * 768 + quad * 8];

        f32x4 s[13];
        #pragma unroll
        for (int ct = 0; ct < 13; ct++) {
            bf16x8 bk = *(const bf16x8*)&Kb[(ct * 16 + l16) * 32 + quad * 8];
            s[ct] = __builtin_amdgcn_mfma_f32_16x16x32_bf16(aq, bk, (f32x4){0.f, 0.f, 0.f, 0.f}, 0, 0, 0);
        }
        if (l16 >= 4) {
            #pragma unroll
            for (int r = 0; r < 4; r++) s[12][r] = -1e30f;
        }
        float mx[4] = {-1e30f, -1e30f, -1e30f, -1e30f};
        #pragma unroll
        for (int ct = 0; ct < 13; ct++)
            #pragma unroll
            for (int r = 0; r < 4; r++) mx[r] = fmaxf(mx[r], s[ct][r]);
        #pragma unroll
        for (int off = 1; off < 16; off <<= 1)
            #pragma unroll
            for (int r = 0; r < 4; r++) mx[r] = fmaxf(mx[r], __shfl_xor(mx[r], off, 64));
        float sum[4] = {0.f, 0.f, 0.f, 0.f};
        #pragma unroll
        for (int ct = 0; ct < 13; ct++) {
            #pragma unroll
            for (int r = 0; r < 4; r++) {
                float p = __expf((s[ct][r] - mx[r]) * scale);
                sum[r] += p;
                Pl[wave][(quad * 4 + r) * 232 + ct * 16 + l16] = f2b(p);
            }
        }
        #pragma unroll
        for (int off = 1; off < 16; off <<= 1)
            #pragma unroll
            for (int r = 0; r < 4; r++) sum[r] += __shfl_xor(sum[r], off, 64);
        float inv[4];
        #pragma unroll
        for (int r = 0; r < 4; r++) inv[r] = 1.f / sum[r];

        #pragma unroll
        for (int nt = 0; nt < 2; nt++) {
            f32x4 ao = {0.f, 0.f, 0.f, 0.f};
            #pragma unroll
            for (int kc = 0; kc < 7; kc++) {
                bf16x8 ap = *(const bf16x8*)&Pl[wave][l16 * 232 + kc * 32 + quad * 8];
                bf16x8 bv = *(const bf16x8*)&Vt[(nt * 16 + l16) * 232 + kc * 32 + quad * 8];
                ao = __builtin_amdgcn_mfma_f32_16x16x32_bf16(ap, bv, ao, 0, 0, 0);
            }
            #pragma unroll
            for (int r = 0; r < 4; r++) {
                const int gm = m0 + quad * 4 + r;
                if (gm < 196)
                    o[((size_t)b * 196 + gm) * 256 + h * 32 + nt * 16 + l16] = f2b(ao[r] * inv[r]);
            }
        }
    }
}

// ---------------------------------------------------------------------------
extern "C" void kernel_launch(void* const* d_in, const int* in_sizes, int n_in,
                              void* d_out, int out_size, void* d_ws, size_t ws_size,
                              hipStream_t stream) {
    const float* x      = (const float*)d_in[0];
    const float* Wqkv   = (const float*)d_in[1];
    const float* bqkv   = (const float*)d_in[2];
    const float* Wproj  = (const float*)d_in[3];
    const float* bproj  = (const float*)d_in[4];
    const float* W1     = (const float*)d_in[5];
    const float* b1     = (const float*)d_in[6];
    const float* W2     = (const float*)d_in[7];
    const float* b2     = (const float*)d_in[8];
    const float* saw    = (const float*)d_in[9];
    const float* sab    = (const float*)d_in[10];
    const float* alpha1 = (const float*)d_in[11];
    const float* g1     = (const float*)d_in[12];
    const float* be1    = (const float*)d_in[13];
    const float* rm1    = (const float*)d_in[14];
    const float* rv1    = (const float*)d_in[15];
    const float* alpha2 = (const float*)d_in[16];
    const float* g2     = (const float*)d_in[17];
    const float* be2    = (const float*)d_in[18];
    const float* rm2    = (const float*)d_in[19];
    const float* rv2    = (const float*)d_in[20];

    const int B = 256, Cc = 256, Np = 196, CM = 2048;
    const int M = B * Np; // 50176

    auto al = [](size_t s) { return (s + 255) & ~(size_t)255; };
    char* ws = (char*)d_ws;
    const size_t o_t0  = 0;
    const size_t o_t1  = o_t0 + al((size_t)M * Cc * 2);
    const size_t o_wq  = o_t1 + al((size_t)M * Cc * 2);
    const size_t o_wp  = o_wq + al((size_t)768 * Cc * 2);
    const size_t o_w1  = o_wp + al((size_t)Cc * Cc * 2);
    const size_t o_w2  = o_w1 + al((size_t)Cc * CM * 2);
    const size_t o_scr = o_w2 + al((size_t)CM * Cc * 2);
    const size_t S = (ws_size > o_scr) ? ws_size - o_scr : 0;

    u16* t0     = (u16*)(ws + o_t0);
    u16* t1b    = (u16*)(ws + o_t1);
    u16* WqkvT  = (u16*)(ws + o_wq);
    u16* WprojT = (u16*)(ws + o_wp);
    u16* W1T    = (u16*)(ws + o_w1);
    u16* W2T    = (u16*)(ws + o_w2);
    u16* scr    = (u16*)(ws + o_scr);
    u16* t2     = t0;            // alias: t0 dead after proj epilogue
    u16* obuf   = (u16*)d_out;   // bf16 scratch in f32 d_out; fully rewritten by final btrans
    float* out  = (float*)d_out;

    // chunk counts: M-chunks multiples of 256 (gemm_bt W2 uses 256-row tiles).
    int nq = 1; while (nq < 4 && ((size_t)(M / nq) * 768 * 2) > S) nq *= 2;
    const int nf_opts[6] = {1, 2, 4, 14, 28, 56};
    int nf = 56;
    for (int i = 0; i < 6; ++i) {
        if (((size_t)(M / nf_opts[i]) * CM * 2) <= S) { nf = nf_opts[i]; break; }
    }
    const int Mq = M / nq, Bq = B / nq;
    const int Mf = M / nf;

    dim3 tb(32, 8, 1);
    btrans_f2b<<<dim3((Np + 31) / 32, (Cc + 31) / 32, B), tb, 0, stream>>>(x, t0, Cc, Np);
    btrans_f2b<<<dim3(768 / 32, Cc / 32, 1), tb, 0, stream>>>(Wqkv,  WqkvT,  Cc, 768);
    btrans_f2b<<<dim3(Cc  / 32, Cc / 32, 1), tb, 0, stream>>>(Wproj, WprojT, Cc, Cc);
    btrans_f2b<<<dim3(CM  / 32, Cc / 32, 1), tb, 0, stream>>>(W1,    W1T,    Cc, CM);
    btrans_f2b<<<dim3(Cc  / 32, CM / 32, 1), tb, 0, stream>>>(W2,    W2T,    CM, Cc);

    // qkv + attention, chunked over batches (K=256 -> gemm_bres)
    for (int c = 0; c < nq; ++c) {
        const int Hq = Mq / 64;
        const int Gq = (Hq < 98) ? Hq : 98;
        gemm_bres<0><<<dim3(768 / 128, Gq), 512, 0, stream>>>(
            t0 + (size_t)c * Mq * Cc, WqkvT, bqkv, scr, 768, Hq, 0,
            nullptr, nullptr, nullptr, nullptr, nullptr, nullptr, nullptr, nullptr);
        attn_kernel<<<dim3(Bq * 8), 256, 0, stream>>>(scr, obuf + (size_t)c * Mq * Cc);
    }

    // t1 = RepBN1(t0 + obuf @ Wproj + bproj)  (K=256 -> gemm_bres)
    {
        const int Hp = M / 64;
        const int Gp = (Hp < 392) ? Hp : 392;
        gemm_bres<1><<<dim3(Cc / 128, Gp), 512, 0, stream>>>(
            obuf, WprojT, bproj, t1b, Cc, Hp, 0,
            t0, g1, be1, rm1, rv1, alpha1, nullptr, nullptr);
    }

    // FFN: W1 (K=256 -> gemm_bres), W2 (K=2048 -> gemm_bt)
    for (int c = 0; c < nf; ++c) {
        const int Hf = Mf / 64;
        const int Gf = (Hf < 49) ? Hf : 49;
        gemm_bres<2><<<dim3(CM / 128, Gf), 512, 0, stream>>>(
            t1b + (size_t)c * Mf * Cc, W1T, b1, scr, CM, Hf, c * Mf,
            nullptr, nullptr, nullptr, nullptr, nullptr, nullptr, saw, sab);
        gemm_bt<1><<<dim3(Cc / 128, Mf / 256), 512, 0, stream>>>(
            scr, W2T, b2, t2 + (size_t)c * Mf * Cc, Mf, Cc, CM, 0,
            t1b + (size_t)c * Mf * Cc, g2, be2, rm2, rv2, alpha2, nullptr, nullptr);
    }

    // t2 bf16 [B][N][C] -> out f32 [B][C][N]
    btrans_b2f<<<dim3((Cc + 31) / 32, (Np + 31) / 32, B), tb, 0, stream>>>(t2, out, Np, Cc);
}

// Round 8
// 515.228 us; speedup vs baseline: 1.5187x; 1.4629x over previous
//
#include <hip/hip_runtime.h>

using u16 = unsigned short;

typedef __bf16 bf16x8 __attribute__((ext_vector_type(8)));
typedef u16    u16x8  __attribute__((ext_vector_type(8)));
typedef float  f32x4  __attribute__((ext_vector_type(4)));

__device__ __forceinline__ float b2f(u16 u) {
    union { unsigned int i; float f; } c; c.i = ((unsigned int)u) << 16; return c.f;
}
__device__ __forceinline__ u16 f2b(float f) {
    union { float f; unsigned int i; } c; c.f = f;
    unsigned int i = c.i;
    return (u16)((i + 0x7FFFu + ((i >> 16) & 1u)) >> 16);
}
__device__ __forceinline__ unsigned cvtpk(float lo, float hi) {
    unsigned d;
    asm("v_cvt_pk_bf16_f32 %0, %1, %2" : "=v"(d) : "v"(lo), "v"(hi));
    return d;
}

#define AS1 __attribute__((address_space(1)))
#define AS3 __attribute__((address_space(3)))
__device__ __forceinline__ void glds16(const u16* g, u16* l) {
    __builtin_amdgcn_global_load_lds((const AS1 void*)(const void*)g,
                                     (AS3 void*)(void*)l, 16, 0, 0);
}

// ---------------------------------------------------------------------------
// Batched transpose + convert f32 -> bf16: in[b][R][C] f32 -> out[b][C][R] bf16
// ---------------------------------------------------------------------------
__global__ void btrans_f2b(const float* __restrict__ in, u16* __restrict__ out, int R, int C) {
    __shared__ u16 tile[32][33];
    const int c0 = blockIdx.x * 32, r0 = blockIdx.y * 32;
    const size_t base = (size_t)blockIdx.z * R * C;
    const int tx = threadIdx.x, ty = threadIdx.y;
    #pragma unroll
    for (int i = ty; i < 32; i += 8) {
        int r = r0 + i, c = c0 + tx;
        tile[i][tx] = (r < R && c < C) ? f2b(in[base + (size_t)r * C + c]) : (u16)0;
    }
    __syncthreads();
    #pragma unroll
    for (int i = ty; i < 32; i += 8) {
        int c = c0 + i, r = r0 + tx;
        if (c < C && r < R) out[base + (size_t)c * R + r] = tile[tx][i];
    }
}

// Batched transpose + convert bf16 -> f32: in[b][R][C] bf16 -> out[b][C][R] f32
__global__ void btrans_b2f(const u16* __restrict__ in, float* __restrict__ out, int R, int C) {
    __shared__ u16 tile[32][33];
    const int c0 = blockIdx.x * 32, r0 = blockIdx.y * 32;
    const size_t base = (size_t)blockIdx.z * R * C;
    const int tx = threadIdx.x, ty = threadIdx.y;
    #pragma unroll
    for (int i = ty; i < 32; i += 8) {
        int r = r0 + i, c = c0 + tx;
        tile[i][tx] = (r < R && c < C) ? in[base + (size_t)r * C + c] : (u16)0;
    }
    __syncthreads();
    #pragma unroll
    for (int i = ty; i < 32; i += 8) {
        int c = c0 + i, r = r0 + tx;
        if (c < C && r < R) out[base + (size_t)c * R + r] = b2f(tile[tx][i]);
    }
}

// ---------------------------------------------------------------------------
// GEMM: C[M,N] = epilogue(A[M,K] @ BT[N,K]^T + bias)   (A,BT,C bf16)
// R9 (proven 526 us): 256x128 block tile, BK=32, 8 waves (4M x 2N), 64x64
// per-wave tiles. 2-buffer, one-__syncthreads-per-K-step skeleton.
// LDS 48 KB (A 2x16K, B 2x8K). Epilogue: cross-lane pair pack + dword stores.
// EPI=1 residual restaged through LDS in two 128-row halves. EPI=2 /196
// hoisted per (i,r). XCD-aware bijective block swizzle. BK=32 LDS k-chunks
// XOR-swizzled (conflict-free: row stride 64B keeps rows in the bank bits).
// EPI: 0 = bias only; 1 = bias+residual+RepBN; 2 = bias+SpatialSiLU
// ---------------------------------------------------------------------------
template<int EPI>
__launch_bounds__(512, 4)
__global__ void gemm_bt(const u16* __restrict__ A, const u16* __restrict__ BT,
                        const float* __restrict__ bias, u16* __restrict__ C,
                        int M, int N, int K, int row0,
                        const u16* __restrict__ R0,
                        const float* __restrict__ g, const float* __restrict__ be,
                        const float* __restrict__ rmv, const float* __restrict__ rvv,
                        const float* __restrict__ alpha,
                        const float* __restrict__ saw, const float* __restrict__ sab) {
    // A buffers: [0, 16384) = 2 x 8192 (256 rows x 32); B: [16384, 24576) = 2 x 4096
    __shared__ __align__(16) u16 SL[24576];  // 48 KB
    const int tid  = threadIdx.x;
    const int wave = tid >> 6, lane = tid & 63;
    const int wm = wave >> 1, wn = wave & 1;      // 4M x 2N wave grid
    const int quad = lane >> 4, l16 = lane & 15;

    // XCD-aware bijective block swizzle (m204)
    const unsigned gx = gridDim.x;
    unsigned lin = blockIdx.y * gx + blockIdx.x;
    const unsigned nwg = gx * gridDim.y;
    const unsigned q8 = nwg >> 3, r8 = nwg & 7;
    const unsigned xcd = lin & 7, loc = lin >> 3;
    lin = (xcd < r8 ? xcd * (q8 + 1) : r8 * (q8 + 1) + (xcd - r8) * q8) + loc;
    const int m0 = (int)(lin / gx) * 256, n0 = (int)(lin % gx) * 128;

    // staging: wave stages A rows [wave*32,+32) (2 loads) and B rows [wave*16,+16).
    const int srow = lane >> 2;                                   // 0..15
    const int scol = (((lane & 3) ^ ((srow >> 1) & 3)) * 8);      // swizzled source chunk
    const size_t aoff0 = (size_t)(m0 + wave * 32 + srow) * K + scol;
    const size_t aoff1 = aoff0 + (size_t)16 * K;
    const size_t boff  = (size_t)(n0 + wave * 16 + srow) * K + scol;

    // fragment read column (undo swizzle): global chunk = quad
    const int cfrag = (quad ^ ((l16 >> 1) & 3)) * 8;

    f32x4 acc[4][4] = {};
    const int niter = K >> 5;

    auto stage = [&](int buf, size_t kn) {
        glds16(A  + aoff0 + kn, SL + buf * 8192 + wave * 1024);
        glds16(A  + aoff1 + kn, SL + buf * 8192 + wave * 1024 + 512);
        glds16(BT + boff  + kn, SL + 16384 + buf * 4096 + wave * 512);
    };

    auto kstep = [&](int cur, int kt) {
        __syncthreads();  // drains vmcnt(0): buf[cur] ready; buf[cur^1] readers done
        if (kt + 1 < niter) stage(cur ^ 1, (size_t)(kt + 1) << 5);
        const u16* ab = SL + cur * 8192;
        const u16* bb = SL + 16384 + cur * 4096;
        bf16x8 af[4], bfr[4];
        #pragma unroll
        for (int i = 0; i < 4; i++)
            af[i] = *(const bf16x8*)&ab[(wm * 64 + i * 16 + l16) * 32 + cfrag];
        #pragma unroll
        for (int j = 0; j < 4; j++)
            bfr[j] = *(const bf16x8*)&bb[(wn * 64 + j * 16 + l16) * 32 + cfrag];
        #pragma unroll
        for (int i = 0; i < 4; i++)
            #pragma unroll
            for (int j = 0; j < 4; j++)
                acc[i][j] = __builtin_amdgcn_mfma_f32_16x16x32_bf16(af[i], bfr[j], acc[i][j], 0, 0, 0);
    };

    // prologue: issue tile 0 into buffer 0
    stage(0, 0);
    int kt = 0;
    for (; kt + 2 <= niter; kt += 2) { kstep(0, kt); kstep(1, kt + 1); }
    if (kt < niter) kstep(kt & 1, kt);

    // ---------------- epilogue ----------------
    __syncthreads();  // all K-loop LDS reads done before any reuse of SL

    float alphav = 0.f;
    if (EPI == 1) alphav = alpha[0];

    // per-column (j) constants
    float biasv[4], k0v[4], k1v[4];
    #pragma unroll
    for (int j = 0; j < 4; j++) {
        const int col = n0 + wn * 64 + j * 16 + l16;
        biasv[j] = bias[col];
        if (EPI == 1) {
            float sc = g[col] * rsqrtf(rvv[col] + 1e-5f);
            k1v[j] = sc + alphav;
            k0v[j] = be[col] - rmv[col] * sc;
        }
    }

    const int dup = l16 & 1;            // which row-pair this lane stores
    const int pr  = l16 >> 1;           // column pair index (0..7)
    u16* Crow = C + (size_t)(m0 + wm * 64 + quad * 4 + 2 * dup) * N
                  + (n0 + wn * 64 + pr * 2);

    auto emit = [&]() {
        #pragma unroll
        for (int i = 0; i < 4; i++) {
            float swv4[4], sbv4[4];
            if (EPI == 2) {
                #pragma unroll
                for (int r = 0; r < 4; r++) {
                    const int row = row0 + m0 + wm * 64 + i * 16 + quad * 4 + r;
                    const int bidx = row / 196;
                    swv4[r] = saw[bidx]; sbv4[r] = sab[bidx];
                }
            }
            #pragma unroll
            for (int j = 0; j < 4; j++) {
                float vv[4];
                #pragma unroll
                for (int r = 0; r < 4; r++) {
                    float v = acc[i][j][r] + biasv[j];
                    if (EPI == 1) {
                        const int rowL = (wm & 1) * 64 + i * 16 + quad * 4 + r;
                        const int colp = wn * 64 + j * 16 + (l16 & ~1);
                        unsigned rd = *(const unsigned*)&SL[rowL * 128 + colp];
                        unsigned fb = dup ? (rd & 0xffff0000u) : (rd << 16);
                        union { unsigned u; float f; } cc; cc.u = fb;
                        float x = v + cc.f;
                        v = fmaf(x, k1v[j], k0v[j]);
                    } else if (EPI == 2) {
                        float w = fmaf(swv4[r], v, sbv4[r]);
                        v = v / (1.f + __expf(-w * v));
                    }
                    vv[r] = v;
                }
                // cross-lane pair pack -> dword stores
                unsigned D[4];
                #pragma unroll
                for (int r = 0; r < 4; r++) {
                    float o  = __shfl_xor(vv[r], 1, 64);
                    float lo = dup ? o : vv[r];
                    float hi = dup ? vv[r] : o;
                    D[r] = cvtpk(lo, hi);
                }
                unsigned s0 = dup ? D[2] : D[0];
                unsigned s1 = dup ? D[3] : D[1];
                u16* p = Crow + (size_t)i * 16 * N + j * 16;
                *(unsigned*)p       = s0;
                *(unsigned*)(p + N) = s1;
            }
        }
    };

    if (EPI == 1) {
        // residual tile [256][128] restaged in two 128-row halves
        #pragma unroll
        for (int h = 0; h < 2; h++) {
            for (int c = tid; c < 2048; c += 512) {
                int row = c >> 4, colc = (c & 15) * 8;
                *(u16x8*)&SL[row * 128 + colc] =
                    *(const u16x8*)&R0[(size_t)(m0 + h * 128 + row) * N + n0 + colc];
            }
            __syncthreads();
            if ((wm >> 1) == h) emit();   // waves wm 0,1 -> half 0; wm 2,3 -> half 1
            __syncthreads();
        }
    } else {
        emit();
    }
}

// ---------------------------------------------------------------------------
// MFMA flash attention: one block per (local b, h), 4 waves.
// V staging vectorized (u16x8 row reads + scalar transposed LDS writes).
// ---------------------------------------------------------------------------
__launch_bounds__(256)
__global__ void attn_kernel(const u16* __restrict__ qkv, u16* __restrict__ o) {
    __shared__ __align__(16) u16 Kb[224 * 32];
    __shared__ __align__(16) u16 Vt[32 * 232];
    __shared__ __align__(16) u16 Pl[4][16 * 232];
    const int tid  = threadIdx.x;
    const int wave = tid >> 6, lane = tid & 63;
    const int quad = lane >> 4, l16 = lane & 15;
    const int b = blockIdx.x >> 3, h = blockIdx.x & 7;
    const u16* qg = qkv + (size_t)b * 196 * 768 + h * 32;
    const float scale = 0.17677669529663687f; // 1/sqrt(32)

    for (int idx = tid; idx < 896; idx += 256) {
        int row = idx >> 2, dp = (idx & 3) * 8;
        u16x8 kv = {};
        if (row < 196) kv = *(const u16x8*)&qg[(size_t)row * 768 + 256 + dp];
        *(u16x8*)&Kb[row * 32 + dp] = kv;
    }
    for (int idx = tid; idx < 896; idx += 256) {  // V: vector read, transposed scalar LDS writes
        int row = idx >> 2, dp = (idx & 3) * 8;
        u16x8 vv = {};
        if (row < 196) vv = *(const u16x8*)&qg[(size_t)row * 768 + 512 + dp];
        #pragma unroll
        for (int e = 0; e < 8; e++) Vt[(dp + e) * 232 + row] = vv[e];
    }
    for (int c = lane; c < 16 * 24; c += 64) {
        int m = c / 24, cc = 208 + (c % 24);
        Pl[wave][m * 232 + cc] = 0;
    }
    __syncthreads();

    for (int t = wave; t < 13; t += 4) {
        const int m0 = t * 16;
        bf16x8 aq = {};
        const int qrow = m0 + l16;
        if (qrow < 196) aq = *(const bf16x8*)&qg[(size_t)qrow * 768 + quad * 8];

        f32x4 s[13];
        #pragma unroll
        for (int ct = 0; ct < 13; ct++) {
            bf16x8 bk = *(const bf16x8*)&Kb[(ct * 16 + l16) * 32 + quad * 8];
            s[ct] = __builtin_amdgcn_mfma_f32_16x16x32_bf16(aq, bk, (f32x4){0.f, 0.f, 0.f, 0.f}, 0, 0, 0);
        }
        if (l16 >= 4) {
            #pragma unroll
            for (int r = 0; r < 4; r++) s[12][r] = -1e30f;
        }
        float mx[4] = {-1e30f, -1e30f, -1e30f, -1e30f};
        #pragma unroll
        for (int ct = 0; ct < 13; ct++)
            #pragma unroll
            for (int r = 0; r < 4; r++) mx[r] = fmaxf(mx[r], s[ct][r]);
        #pragma unroll
        for (int off = 1; off < 16; off <<= 1)
            #pragma unroll
            for (int r = 0; r < 4; r++) mx[r] = fmaxf(mx[r], __shfl_xor(mx[r], off, 64));
        float sum[4] = {0.f, 0.f, 0.f, 0.f};
        #pragma unroll
        for (int ct = 0; ct < 13; ct++) {
            #pragma unroll
            for (int r = 0; r < 4; r++) {
                float p = __expf((s[ct][r] - mx[r]) * scale);
                sum[r] += p;
                Pl[wave][(quad * 4 + r) * 232 + ct * 16 + l16] = f2b(p);
            }
        }
        #pragma unroll
        for (int off = 1; off < 16; off <<= 1)
            #pragma unroll
            for (int r = 0; r < 4; r++) sum[r] += __shfl_xor(sum[r], off, 64);
        float inv[4];
        #pragma unroll
        for (int r = 0; r < 4; r++) inv[r] = 1.f / sum[r];

        #pragma unroll
        for (int nt = 0; nt < 2; nt++) {
            f32x4 ao = {0.f, 0.f, 0.f, 0.f};
            #pragma unroll
            for (int kc = 0; kc < 7; kc++) {
                bf16x8 ap = *(const bf16x8*)&Pl[wave][l16 * 232 + kc * 32 + quad * 8];
                bf16x8 bv = *(const bf16x8*)&Vt[(nt * 16 + l16) * 232 + kc * 32 + quad * 8];
                ao = __builtin_amdgcn_mfma_f32_16x16x32_bf16(ap, bv, ao, 0, 0, 0);
            }
            #pragma unroll
            for (int r = 0; r < 4; r++) {
                const int gm = m0 + quad * 4 + r;
                if (gm < 196)
                    o[((size_t)b * 196 + gm) * 256 + h * 32 + nt * 16 + l16] = f2b(ao[r] * inv[r]);
            }
        }
    }
}

// ---------------------------------------------------------------------------
extern "C" void kernel_launch(void* const* d_in, const int* in_sizes, int n_in,
                              void* d_out, int out_size, void* d_ws, size_t ws_size,
                              hipStream_t stream) {
    const float* x      = (const float*)d_in[0];
    const float* Wqkv   = (const float*)d_in[1];
    const float* bqkv   = (const float*)d_in[2];
    const float* Wproj  = (const float*)d_in[3];
    const float* bproj  = (const float*)d_in[4];
    const float* W1     = (const float*)d_in[5];
    const float* b1     = (const float*)d_in[6];
    const float* W2     = (const float*)d_in[7];
    const float* b2     = (const float*)d_in[8];
    const float* saw    = (const float*)d_in[9];
    const float* sab    = (const float*)d_in[10];
    const float* alpha1 = (const float*)d_in[11];
    const float* g1     = (const float*)d_in[12];
    const float* be1    = (const float*)d_in[13];
    const float* rm1    = (const float*)d_in[14];
    const float* rv1    = (const float*)d_in[15];
    const float* alpha2 = (const float*)d_in[16];
    const float* g2     = (const float*)d_in[17];
    const float* be2    = (const float*)d_in[18];
    const float* rm2    = (const float*)d_in[19];
    const float* rv2    = (const float*)d_in[20];

    const int B = 256, Cc = 256, Np = 196, CM = 2048;
    const int M = B * Np; // 50176

    auto al = [](size_t s) { return (s + 255) & ~(size_t)255; };
    char* ws = (char*)d_ws;
    const size_t o_t0  = 0;
    const size_t o_t1  = o_t0 + al((size_t)M * Cc * 2);
    const size_t o_wq  = o_t1 + al((size_t)M * Cc * 2);
    const size_t o_wp  = o_wq + al((size_t)768 * Cc * 2);
    const size_t o_w1  = o_wp + al((size_t)Cc * Cc * 2);
    const size_t o_w2  = o_w1 + al((size_t)Cc * CM * 2);
    const size_t o_scr = o_w2 + al((size_t)CM * Cc * 2);
    const size_t S = (ws_size > o_scr) ? ws_size - o_scr : 0;

    u16* t0     = (u16*)(ws + o_t0);
    u16* t1b    = (u16*)(ws + o_t1);
    u16* WqkvT  = (u16*)(ws + o_wq);
    u16* WprojT = (u16*)(ws + o_wp);
    u16* W1T    = (u16*)(ws + o_w1);
    u16* W2T    = (u16*)(ws + o_w2);
    u16* scr    = (u16*)(ws + o_scr);
    u16* t2     = t0;            // alias: t0 dead after proj epilogue
    u16* obuf   = (u16*)d_out;   // bf16 scratch in f32 d_out; fully rewritten by final btrans
    float* out  = (float*)d_out;

    // chunk counts: M-chunks must stay multiples of 256.
    int nq = 1; while (nq < 4 && ((size_t)(M / nq) * 768 * 2) > S) nq *= 2;
    const int nf_opts[6] = {1, 2, 4, 14, 28, 56};
    int nf = 56;
    for (int i = 0; i < 6; ++i) {
        if (((size_t)(M / nf_opts[i]) * CM * 2) <= S) { nf = nf_opts[i]; break; }
    }
    const int Mq = M / nq, Bq = B / nq;
    const int Mf = M / nf;

    dim3 tb(32, 8, 1);
    // x f32 [B][C][N] -> t0 bf16 [B][N][C]
    btrans_f2b<<<dim3((Np + 31) / 32, (Cc + 31) / 32, B), tb, 0, stream>>>(x, t0, Cc, Np);
    // weights f32 [K][N] -> bf16 [N][K]
    btrans_f2b<<<dim3(768 / 32, Cc / 32, 1), tb, 0, stream>>>(Wqkv,  WqkvT,  Cc, 768);
    btrans_f2b<<<dim3(Cc  / 32, Cc / 32, 1), tb, 0, stream>>>(Wproj, WprojT, Cc, Cc);
    btrans_f2b<<<dim3(CM  / 32, Cc / 32, 1), tb, 0, stream>>>(W1,    W1T,    Cc, CM);
    btrans_f2b<<<dim3(Cc  / 32, CM / 32, 1), tb, 0, stream>>>(W2,    W2T,    CM, Cc);

    // qkv + attention, chunked over batches
    for (int c = 0; c < nq; ++c) {
        gemm_bt<0><<<dim3(768 / 128, Mq / 256), 512, 0, stream>>>(
            t0 + (size_t)c * Mq * Cc, WqkvT, bqkv, scr, Mq, 768, Cc, 0,
            nullptr, nullptr, nullptr, nullptr, nullptr, nullptr, nullptr, nullptr);
        attn_kernel<<<dim3(Bq * 8), 256, 0, stream>>>(scr, obuf + (size_t)c * Mq * Cc);
    }

    // t1 = RepBN1(t0 + obuf @ Wproj + bproj)
    gemm_bt<1><<<dim3(Cc / 128, M / 256), 512, 0, stream>>>(
        obuf, WprojT, bproj, t1b, M, Cc, Cc, 0,
        t0, g1, be1, rm1, rv1, alpha1, nullptr, nullptr);

    // FFN, chunked over rows
    for (int c = 0; c < nf; ++c) {
        gemm_bt<2><<<dim3(CM / 128, Mf / 256), 512, 0, stream>>>(
            t1b + (size_t)c * Mf * Cc, W1T, b1, scr, Mf, CM, Cc, c * Mf,
            nullptr, nullptr, nullptr, nullptr, nullptr, nullptr, saw, sab);
        gemm_bt<1><<<dim3(Cc / 128, Mf / 256), 512, 0, stream>>>(
            scr, W2T, b2, t2 + (size_t)c * Mf * Cc, Mf, Cc, CM, 0,
            t1b + (size_t)c * Mf * Cc, g2, be2, rm2, rv2, alpha2, nullptr, nullptr);
    }

    // t2 bf16 [B][N][C] -> out f32 [B][C][N]
    btrans_b2f<<<dim3((Cc + 31) / 32, (Np + 31) / 32, B), tb, 0, stream>>>(t2, out, Np, Cc);
}